// Round 21
// baseline (381.109 us; speedup 1.0000x reference)
//
#include <hip/hip_runtime.h>
#include <math.h>
#include <stddef.h>

#define N0   4096
#define NE   131072
#define FIN  1433
#define HID  32
#define NCLS 16
#define KP1  2000
#define KP2  1000
#define KP3  500
#define RCH  512

typedef __attribute__((ext_vector_type(8))) short bf16x8;
typedef __attribute__((ext_vector_type(4))) float f32x4;

// ---------------- basic utils ----------------

__global__ __launch_bounds__(256) void k_fill0_u32(unsigned* p, size_t n) {
    size_t i = (size_t)blockIdx.x * blockDim.x + threadIdx.x;
    size_t st = (size_t)gridDim.x * blockDim.x;
    for (; i < n; i += st) p[i] = 0u;
}

// count out-degrees only
__global__ __launch_bounds__(256) void k_scatcnt(const int* ei, int* ecnt) {
    int e = blockIdx.x * blockDim.x + threadIdx.x;
    if (e >= NE) return;
    int r = ei[e], c = ei[NE + e];
    if (r == c) return;
    atomicAdd(&ecnt[r], 1);
}

// exclusive prefix scan of one N0-length int array; optionally emits dv[i]=1/sqrt(d[i]+2)
__global__ __launch_bounds__(256) void k_scan1(const int* __restrict__ d, int* __restrict__ o,
                                               float* __restrict__ dv) {
    __shared__ int buf[N0];
    __shared__ int part[256];
    int tid = threadIdx.x;
    for (int t = tid; t < N0; t += 256) buf[t] = d[t];
    __syncthreads();
    int base = tid * (N0 / 256);
    int s = 0;
    #pragma unroll
    for (int j = 0; j < N0 / 256; j++) s += buf[base + j];
    part[tid] = s;
    __syncthreads();
    for (int offd = 1; offd < 256; offd <<= 1) {
        int v = (tid >= offd) ? part[tid - offd] : 0;
        __syncthreads();
        part[tid] += v;
        __syncthreads();
    }
    int run = (tid == 0) ? 0 : part[tid - 1];
    #pragma unroll
    for (int j = 0; j < N0 / 256; j++) {
        int tmp = buf[base + j];
        o[base + j] = run;
        run += tmp;
    }
    if (dv) {
        for (int t = tid; t < N0; t += 256)
            dv[t] = (float)(1.0 / sqrt((double)buf[t] + 2.0));
    }
}

// fill unfiltered out-CSR
__global__ __launch_bounds__(256) void k_fillout(const int* ei, const int* outoff, int* ocur, int* outlist) {
    int e = blockIdx.x * 256 + threadIdx.x;
    if (e >= NE) return;
    int u = ei[e], v = ei[NE + e];
    if (u == v) return;
    int s = atomicAdd(&ocur[u], 1);
    outlist[outoff[u] + s] = v;
}

// filtered counts: edges u->v with rk[v]<KP1
__global__ __launch_bounds__(256) void k_fcount(const int* ei, const int* rk, int* focnt) {
    int e = blockIdx.x * 256 + threadIdx.x;
    if (e >= NE) return;
    int u = ei[e], v = ei[NE + e];
    if (u == v) return;
    if (rk[v] < KP1) atomicAdd(&focnt[u], 1);
}

// fill filtered, rank-remapped out-lists
__global__ __launch_bounds__(256) void k_ffill(const int* ei, const int* rk, const int* foutoff,
                                               int* fcur, int* foutlist) {
    int e = blockIdx.x * 256 + threadIdx.x;
    if (e >= NE) return;
    int u = ei[e], v = ei[NE + e];
    if (u == v) return;
    int rv = rk[v];
    if (rv >= KP1) return;
    int s = atomicAdd(&fcur[u], 1);
    foutlist[foutoff[u] + s] = rv;
}

// row-centric sparse augment: A1[r1][:] = ((A0+I)^2)[perm[r1]][perm[:]], diag 0; dv1 fused.
// group-parallel inner loop: 8 groups x 32 lanes per k.
__global__ __launch_bounds__(256) void k_spaug2(const int* __restrict__ ecnt, const int* __restrict__ outoff,
                                                const int* __restrict__ outlist,
                                                const int* __restrict__ focnt, const int* __restrict__ foutoff,
                                                const int* __restrict__ foutlist,
                                                const int* __restrict__ perm,
                                                float* __restrict__ A1, float* __restrict__ dv1) {
    __shared__ float rowacc[KP1];
    __shared__ float red[256];
    int r1 = blockIdx.x, tid = threadIdx.x;
    for (int j = tid; j < KP1; j += 256) rowacc[j] = 0.f;
    int pr1 = perm[r1];
    __syncthreads();
    int od = ecnt[pr1], ob = outoff[pr1];
    int g = tid >> 5, lane = tid & 31;
    for (int ki = g; ki < od; ki += 8) {
        int k = outlist[ob + ki];
        int fb = foutoff[k], fc = focnt[k];
        for (int j = lane; j < fc; j += 32) atomicAdd(&rowacc[foutlist[fb + j]], 1.f);
    }
    {
        int fb = foutoff[pr1], fc = focnt[pr1];
        for (int j = tid; j < fc; j += 256) atomicAdd(&rowacc[foutlist[fb + j]], 2.f);
    }
    __syncthreads();
    if (tid == 0) rowacc[r1] = 0.f;
    __syncthreads();
    float rs = 0.f;
    for (int j = tid * 4; j < KP1; j += 1024) {
        float4 v = *(const float4*)&rowacc[j];
        rs += v.x + v.y + v.z + v.w;
        *(float4*)&A1[(size_t)r1 * KP1 + j] = v;
    }
    red[tid] = rs; __syncthreads();
    for (int o = 128; o > 0; o >>= 1) {
        if (tid < o) red[tid] += red[tid + o];
        __syncthreads();
    }
    if (tid == 0) dv1[r1] = (float)(1.0 / sqrt((double)red[0] + 2.0));
}

// CSR-gather GCN aggregation over A0 with fused epilogue.
template <int NC, int MODE>
__global__ __launch_bounds__(256) void k_spagg(const int* __restrict__ outoff, const int* __restrict__ ecnt,
                                               const int* __restrict__ outlist,
                                               const float* __restrict__ y, const float* __restrict__ dvv,
                                               const float* __restrict__ bias, float* __restrict__ outp) {
    constexpr int G = 256 / NC;
    __shared__ float red[256];
    __shared__ float fin[NC];
    int i = blockIdx.x;
    int tid = threadIdx.x;
    int c = tid % NC, g = tid / NC;
    int od = ecnt[i], ob = outoff[i];
    float acc = 0.f;
    for (int j = g; j < od; j += G)
        acc += y[(size_t)outlist[ob + j] * NC + c];
    red[tid] = acc;
    __syncthreads();
    for (int o = G / 2; o > 0; o >>= 1) {
        if (g < o) red[tid] += red[tid + o * NC];
        __syncthreads();
    }
    if (tid < NC) {
        float di = dvv[i];
        float v = di * red[tid] + 2.f * di * y[(size_t)i * NC + tid] + bias[tid];
        if (MODE == 0) v = fmaxf(v, 0.f);
        fin[tid] = v;
    }
    __syncthreads();
    if (tid < NC) {
        if (MODE == 2) {
            float m = -1e30f;
            for (int cc = 0; cc < NC; cc++) m = fmaxf(m, fin[cc]);
            float se = 0.f;
            for (int cc = 0; cc < NC; cc++) se += expf(fin[cc] - m);
            outp[(size_t)i * NC + tid] = fin[tid] - m - logf(se);
        } else {
            outp[(size_t)i * NC + tid] = fin[tid];
        }
    }
}

// vectorized deg for f32 adjacency; entries are exact integers
__global__ __launch_bounds__(256) void k_degf(const float* A, int n, float* dv) {
    int i = blockIdx.x;
    const float* row = A + (size_t)i * n;
    float acc = 0.f;
    for (int j = threadIdx.x * 4; j < n; j += 256 * 4) {
        float4 w = *(const float4*)&row[j];
        acc += w.x + w.y + w.z + w.w;
    }
    __shared__ float red[256];
    red[threadIdx.x] = acc; __syncthreads();
    for (int off = 128; off > 0; off >>= 1) {
        if (threadIdx.x < off) red[threadIdx.x] += red[threadIdx.x + off];
        __syncthreads();
    }
    if (threadIdx.x == 0) dv[i] = (float)(1.0 / sqrt((double)red[0] + 2.0));
}

// tiled XW GEMM with fused dv scaling and optional fused unpool
template <int NC>
__global__ __launch_bounds__(256) void k_xw2(const float* __restrict__ X, const float* __restrict__ W,
                                             const float* __restrict__ dvv, float* __restrict__ YB,
                                             int M, int K,
                                             const float* __restrict__ UP, const int* __restrict__ rkl, int kup) {
    constexpr int BR = 256 / NC;
    constexpr int BK = 64;
    constexpr int XEL = BR * BK / 256;
    constexpr int WEL = BK * NC / 256;
    __shared__ float Xs[BR][BK + 4];
    __shared__ float Ws[BK][NC];
    int r0 = blockIdx.x * BR;
    int tid = threadIdx.x;
    int c = tid % NC, r = tid / NC;
    int xli = tid * XEL, xr = xli / BK, xc = xli % BK;
    int wli = tid * WEL, wk = wli / NC, wc = wli % NC;
    int grow = r0 + xr;
    int upr = -1;
    if (UP && grow < M) { int rr = rkl[grow]; if (rr < kup) upr = rr; }
    float acc = 0.f;

    for (int k0 = 0; k0 < K; k0 += BK) {
        __syncthreads();
        #pragma unroll
        for (int e = 0; e < XEL; e++) {
            int kk = k0 + xc + e;
            float v = (grow < M && kk < K) ? X[(size_t)grow * K + kk] : 0.f;
            if (upr >= 0 && kk < K) v += UP[(size_t)upr * K + kk];
            Xs[xr][xc + e] = v;
        }
        if (k0 + wk < K) {
            #pragma unroll
            for (int e = 0; e < WEL; e += 4)
                *(float4*)&Ws[wk][wc + e] = *(const float4*)&W[(size_t)(k0 + wk) * NC + wc + e];
        } else {
            #pragma unroll
            for (int e = 0; e < WEL; e++) Ws[wk][wc + e] = 0.f;
        }
        __syncthreads();
        #pragma unroll 8
        for (int k = 0; k < BK; k++) acc += Xs[r][k] * Ws[k][c];
    }
    int orow = r0 + r;
    if (orow < M) YB[(size_t)orow * NC + c] = dvv[orow] * acc;
}

// split-K variant for the large-K (FIN) layer
__global__ __launch_bounds__(256) void k_xw2sk(const float* __restrict__ X, const float* __restrict__ W,
                                               float* __restrict__ xwp, int M, int K, int chunk) {
    constexpr int NC = 32, BR = 8, BK = 64;
    __shared__ float Xs[BR][BK + 4];
    __shared__ float Ws[BK][NC];
    int r0 = blockIdx.x * BR;
    int s  = blockIdx.y;
    int kb = s * chunk, ke = min(kb + chunk, K);
    int tid = threadIdx.x;
    int c = tid % NC, r = tid / NC;
    int xli = tid * 2, xr = xli / BK, xc = xli % BK;
    int wli = tid * 8, wk = wli / NC, wc = wli % NC;
    int grow = r0 + xr;
    float acc = 0.f;

    for (int k0 = kb; k0 < ke; k0 += BK) {
        __syncthreads();
        #pragma unroll
        for (int e = 0; e < 2; e++) {
            int kk = k0 + xc + e;
            Xs[xr][xc + e] = (grow < M && kk < K) ? X[(size_t)grow * K + kk] : 0.f;
        }
        if (k0 + wk < K) {
            #pragma unroll
            for (int e = 0; e < 8; e += 4)
                *(float4*)&Ws[wk][wc + e] = *(const float4*)&W[(size_t)(k0 + wk) * NC + wc + e];
        } else {
            #pragma unroll
            for (int e = 0; e < 8; e++) Ws[wk][wc + e] = 0.f;
        }
        __syncthreads();
        #pragma unroll 8
        for (int k = 0; k < BK; k++) acc += Xs[r][k] * Ws[k][c];
    }
    int orow = r0 + r;
    if (orow < M) xwp[((size_t)s * M + orow) * NC + c] = acc;
}

// reduce split-K xw partials with dv scaling
__global__ __launch_bounds__(256) void k_xwred(const float* __restrict__ xwp, int S,
                                               const float* __restrict__ dvv, float* __restrict__ yb, int M) {
    int idx = blockIdx.x * 256 + threadIdx.x;
    if (idx >= M * 32) return;
    float s = 0.f;
    for (int t = 0; t < S; t++) s += xwp[(size_t)t * M * 32 + idx];
    yb[idx] = dvv[idx / 32] * s;
}

// ---------------- tiled split-K aggregation (dense f32 levels) ----------------

template <class T, int NC>
__global__ __launch_bounds__(256) void k_agg(const T* __restrict__ A, const float* __restrict__ y,
                                             float* __restrict__ part, int n, int M, int chunk) {
    constexpr int G   = 256 / NC;
    constexpr int RPT = 64 / G;
    __shared__ float At[64][72];
    __shared__ float ys[64][NC];
    int r0 = blockIdx.x * 64;
    int s  = blockIdx.y;
    int k_begin = s * chunk;
    int k_end   = min(k_begin + chunk, n);
    int tid = threadIdx.x;
    int c = tid % NC, g = tid / NC;
    int r = tid & 63, kq = tid >> 6;
    bool row_ok = (r0 + r) < M;
    float acc[RPT] = {};

    for (int k0 = k_begin; k0 < k_end; k0 += 64) {
        __syncthreads();
        #pragma unroll
        for (int q = 0; q < 4; q++) {
            int kl = kq * 16 + q * 4;
            float4 w = {0.f, 0.f, 0.f, 0.f};
            if (row_ok) w = *(const float4*)&A[(size_t)(r0 + r) * n + k0 + kl];
            At[kl + 0][r] = (k0 + kl + 0 < k_end) ? w.x : 0.f;
            At[kl + 1][r] = (k0 + kl + 1 < k_end) ? w.y : 0.f;
            At[kl + 2][r] = (k0 + kl + 2 < k_end) ? w.z : 0.f;
            At[kl + 3][r] = (k0 + kl + 3 < k_end) ? w.w : 0.f;
        }
        constexpr int NF4 = 64 * NC / 4;
        #pragma unroll
        for (int f = 0; f < NF4 / 256; f++) {
            int fi = tid + f * 256;
            int k = fi / (NC / 4), cb = fi % (NC / 4);
            float4 w = *(const float4*)&y[(size_t)(k0 + k) * NC + cb * 4];
            *(float4*)&ys[k][cb * 4] = w;
        }
        __syncthreads();
        for (int k = 0; k < 64; k++) {
            float yv = ys[k][c];
            #pragma unroll
            for (int i = 0; i < RPT; i += 4) {
                float4 a = *(const float4*)&At[k][g * RPT + i];
                acc[i + 0] += a.x * yv;
                acc[i + 1] += a.y * yv;
                acc[i + 2] += a.z * yv;
                acc[i + 3] += a.w * yv;
            }
        }
    }
    #pragma unroll
    for (int i = 0; i < RPT; i++) {
        int row = r0 + g * RPT + i;
        if (row < M) part[((size_t)s * M + row) * NC + c] = acc[i];
    }
}

template <int NC>
__global__ __launch_bounds__(256) void k_aggfin(const float* __restrict__ part, int S,
                                                const float* __restrict__ y, const float* __restrict__ dvv,
                                                const float* __restrict__ bias, float* __restrict__ out,
                                                int M, int relu) {
    int idx = blockIdx.x * blockDim.x + threadIdx.x;
    if (idx >= M * NC) return;
    int i = idx / NC, c = idx % NC;
    float sum = 0.f;
    for (int s = 0; s < S; s++) sum += part[(size_t)s * M * NC + idx];
    float di = dvv[i];
    float v = di * sum + 2.f * di * y[idx] + bias[c];
    if (relu) v = fmaxf(v, 0.f);
    out[idx] = v;
}

// ---------------- top-k pooling ----------------

__global__ __launch_bounds__(256) void k_rankscore(const float* __restrict__ x, const float* __restrict__ p,
                                                   int* __restrict__ rk, int n) {
    __shared__ float sj[RCH];
    float pv[HID];
    #pragma unroll
    for (int c = 0; c < HID; c++) pv[c] = p[c];
    float nrm = 0.f;
    #pragma unroll
    for (int c = 0; c < HID; c++) nrm += pv[c] * pv[c];
    nrm = sqrtf(nrm);
    int jb = blockIdx.y * RCH;
    int len = min(jb + RCH, n) - jb;
    for (int t = threadIdx.x; t < len; t += 256) {
        const float* xr = x + (size_t)(jb + t) * HID;
        float d = 0.f;
        #pragma unroll
        for (int c = 0; c < HID; c++) d += xr[c] * pv[c];
        sj[t] = tanhf(d / nrm);
    }
    __syncthreads();
    int i = blockIdx.x * 256 + threadIdx.x;
    if (i >= n) return;
    const float* xi = x + (size_t)i * HID;
    float di = 0.f;
    #pragma unroll
    for (int c = 0; c < HID; c++) di += xi[c] * pv[c];
    float si = tanhf(di / nrm);
    int r = 0;
    for (int j = 0; j < len; j += 4) {
        float4 v = *(const float4*)&sj[j];
        int jg = jb + j;
        r += (v.x > si) || (v.x == si && (jg + 0) < i);
        r += (v.y > si) || (v.y == si && (jg + 1) < i);
        r += (v.z > si) || (v.z == si && (jg + 2) < i);
        r += (v.w > si) || (v.w == si && (jg + 3) < i);
    }
    atomicAdd(&rk[i], r);
}

__global__ __launch_bounds__(256) void k_permpool2(const float* __restrict__ x, const float* __restrict__ p,
                                                   const int* __restrict__ rk, int* __restrict__ perm,
                                                   float* __restrict__ xp, int n, int k) {
    int i = blockIdx.x * 256 + threadIdx.x;
    if (i >= n) return;
    int r = rk[i];
    if (r >= k) return;
    perm[r] = i;
    float pv[HID];
    #pragma unroll
    for (int c = 0; c < HID; c++) pv[c] = p[c];
    float nrm = 0.f;
    #pragma unroll
    for (int c = 0; c < HID; c++) nrm += pv[c] * pv[c];
    nrm = sqrtf(nrm);
    const float* xi = x + (size_t)i * HID;
    float d = 0.f;
    #pragma unroll
    for (int c = 0; c < HID; c++) d += xi[c] * pv[c];
    float si = tanhf(d / nrm);
    const float4* xr = (const float4*)xi;
    float4* xpo = (float4*)(xp + (size_t)r * HID);
    #pragma unroll
    for (int c = 0; c < HID / 4; c++) {
        float4 v = xr[c];
        v.x *= si; v.y *= si; v.z *= si; v.w *= si;
        xpo[c] = v;
    }
}

// ---------------- fp32 augment+pool path (level 2; split-K) ----------------

template <class T>
__global__ __launch_bounds__(256) void k_gcols(const T* A, const int* perm, T* CG, int n, int kk) {
    size_t idx = (size_t)blockIdx.x * blockDim.x + threadIdx.x;
    if (idx >= (size_t)n * kk) return;
    int k = (int)(idx / kk), r2 = (int)(idx % kk);
    int pc = perm[r2];
    T v = A[(size_t)k * n + pc];
    if (k == pc) v = (T)(v + (T)1);
    CG[idx] = v;
}

__global__ __launch_bounds__(256) void k_gemm_pool_sk(const float* A, const int* perm, const float* CG,
                                                      float* part, int n, int kk, int chunk) {
    __shared__ float As[16][65];
    __shared__ float Bs[16][65];
    __shared__ int   pr[64];
    int r0 = blockIdx.y * 64, c0 = blockIdx.x * 64;
    int s  = blockIdx.z;
    int k_begin = s * chunk;
    int k_end   = min(k_begin + chunk, n);
    int tx = threadIdx.x % 16, ty = threadIdx.x / 16;

    for (int t = threadIdx.x; t < 64; t += 256) {
        int rg = r0 + t;
        pr[t] = (rg < kk) ? perm[rg] : -1;
    }
    __syncthreads();

    float acc[4][4] = {};
    int cB = threadIdx.x % 64, kB = threadIdx.x / 64;

    for (int k0 = k_begin; k0 < k_end; k0 += 16) {
        for (int pass = 0; pass < 4; pass++) {
            int rr = ty + pass * 16;
            int kk_ = k0 + tx;
            int prow = pr[rr];
            float v = 0.f;
            if (prow >= 0 && kk_ < k_end) {
                v = A[(size_t)prow * n + kk_];
                if (prow == kk_) v += 1.f;
            }
            As[tx][rr] = v;
        }
        for (int pass = 0; pass < 4; pass++) {
            int k = kB + 4 * pass;
            int cg = c0 + cB;
            float v = 0.f;
            if (cg < kk && (k0 + k) < k_end) v = CG[(size_t)(k0 + k) * kk + cg];
            Bs[k][cB] = v;
        }
        __syncthreads();
        for (int k = 0; k < 16; k++) {
            float a[4], b[4];
            #pragma unroll
            for (int i = 0; i < 4; i++) a[i] = As[k][ty * 4 + i];
            #pragma unroll
            for (int j = 0; j < 4; j++) b[j] = Bs[k][tx * 4 + j];
            #pragma unroll
            for (int i = 0; i < 4; i++)
                #pragma unroll
                for (int j = 0; j < 4; j++) acc[i][j] += a[i] * b[j];
        }
        __syncthreads();
    }
    for (int i = 0; i < 4; i++) {
        int rg = r0 + ty * 4 + i;
        if (rg >= kk) continue;
        for (int j = 0; j < 4; j++) {
            int cg = c0 + tx * 4 + j;
            if (cg >= kk) continue;
            part[((size_t)s * kk + rg) * kk + cg] = acc[i][j];
        }
    }
}

__global__ __launch_bounds__(256) void k_gpfin(const float* __restrict__ part, int S, float* __restrict__ Ap, int kk) {
    int idx = blockIdx.x * blockDim.x + threadIdx.x;
    if (idx >= kk * kk) return;
    int rg = idx / kk, cg = idx % kk;
    float sum = 0.f;
    for (int s = 0; s < S; s++) sum += part[(size_t)s * kk * kk + idx];
    Ap[idx] = (rg == cg) ? 0.f : sum;
}

// ---------------- MFMA augment+pool path (level 1) ----------------

__global__ __launch_bounds__(256) void k_tr_f32(const float* A, float* AT, int n) {
    __shared__ float t[32][33];
    int bx = blockIdx.x * 32, by = blockIdx.y * 32;
    int tx = threadIdx.x % 32, ty = threadIdx.x / 32;
    for (int p = 0; p < 4; p++) {
        int r = by + ty + p * 8, c = bx + tx;
        t[ty + p * 8][tx] = (r < n && c < n) ? A[(size_t)r * n + c] : 0.f;
    }
    __syncthreads();
    for (int p = 0; p < 4; p++) {
        int r = bx + ty + p * 8, c = by + tx;
        if (r < n && c < n) AT[(size_t)r * n + c] = t[tx][ty + p * 8];
    }
}

// f32 -> bf16 row-gather of (A+I) by perm, both panels in one dispatch
__global__ __launch_bounds__(256) void k_prepfb(const float* A, const float* AT,
                                                int n, int Kpad, const int* perm, int kk,
                                                unsigned short* dstA, unsigned short* dstB) {
    const float* src = blockIdx.y ? AT : A;
    unsigned short* dst = blockIdx.y ? dstB : dstA;
    int r = blockIdx.x;
    unsigned short* drow = dst + (size_t)r * Kpad;
    if (r >= kk) {
        for (int k = threadIdx.x; k < Kpad; k += 256) drow[k] = 0;
        return;
    }
    int pr = perm[r];
    const float* srow = src + (size_t)pr * n;
    for (int k = threadIdx.x; k < Kpad; k += 256) {
        float v = (k < n) ? srow[k] : 0.f;
        if (k == pr) v += 1.f;
        drow[k] = (unsigned short)(__float_as_uint(v) >> 16);
    }
}

// 8-wave 128x128 tile split-K MFMA; exact-integer fp32 atomicAdd; diag skipped (pre-zeroed dst)
__global__ __launch_bounds__(512) void k_mfma_pool(const unsigned short* Abf, const unsigned short* Bbf,
                                                   float* Ap, int Kpad, int kk, int chunk) {
    __shared__ short As[128 * 64];
    __shared__ short Bs[128 * 64];
    int r0 = blockIdx.y * 128, c0 = blockIdx.x * 128;
    int z0 = blockIdx.z * chunk;
    int tid = threadIdx.x;
    int l = tid & 63, w = tid >> 6;
    int wm = w >> 2, wn = w & 3;
    f32x4 acc[4][2] = {};

    for (int k0 = z0; k0 < z0 + chunk; k0 += 64) {
        __syncthreads();
        #pragma unroll
        for (int p = 0; p < 2; p++) {
            int row = p * 64 + (tid >> 3);
            int ch  = tid & 7;
            int byte = row * 128 + ((ch * 16) ^ ((row & 7) << 4));
            bf16x8 va = *(const bf16x8*)&Abf[(size_t)(r0 + row) * Kpad + k0 + ch * 8];
            *(bf16x8*)((char*)As + byte) = va;
            bf16x8 vb = *(const bf16x8*)&Bbf[(size_t)(c0 + row) * Kpad + k0 + ch * 8];
            *(bf16x8*)((char*)Bs + byte) = vb;
        }
        __syncthreads();
        #pragma unroll
        for (int h = 0; h < 2; h++) {
            bf16x8 af[4], bfr[2];
            #pragma unroll
            for (int i = 0; i < 4; i++) {
                int row = wm * 64 + i * 16 + (l & 15);
                int byte = row * 128 + ((h * 64 + (l >> 4) * 16) ^ ((row & 7) << 4));
                af[i] = *(const bf16x8*)((const char*)As + byte);
            }
            #pragma unroll
            for (int j = 0; j < 2; j++) {
                int row = wn * 32 + j * 16 + (l & 15);
                int byte = row * 128 + ((h * 64 + (l >> 4) * 16) ^ ((row & 7) << 4));
                bfr[j] = *(const bf16x8*)((const char*)Bs + byte);
            }
            #pragma unroll
            for (int i = 0; i < 4; i++)
                #pragma unroll
                for (int j = 0; j < 2; j++)
                    acc[i][j] = __builtin_amdgcn_mfma_f32_16x16x32_bf16(af[i], bfr[j], acc[i][j], 0, 0, 0);
        }
    }
    #pragma unroll
    for (int i = 0; i < 4; i++) {
        #pragma unroll
        for (int j = 0; j < 2; j++) {
            int cg = c0 + wn * 32 + j * 16 + (l & 15);
            if (cg < kk) {
                #pragma unroll
                for (int q = 0; q < 4; q++) {
                    int rg = r0 + wm * 64 + i * 16 + (l >> 4) * 4 + q;
                    if (rg < kk && rg != cg) atomicAdd(&Ap[(size_t)rg * kk + cg], acc[i][j][q]);
                }
            }
        }
    }
}

// ---------------- host ----------------

extern "C" void kernel_launch(void* const* d_in, const int* in_sizes, int n_in,
                              void* d_out, int out_size, void* d_ws, size_t ws_size,
                              hipStream_t stream) {
    const float* x  = (const float*)d_in[0];
    const int*   ei = (const int*)d_in[1];
    const float* W0 = (const float*)d_in[2];  const float* b0 = (const float*)d_in[3];
    const float* W1 = (const float*)d_in[4];  const float* b1 = (const float*)d_in[5];
    const float* W2 = (const float*)d_in[6];  const float* b2 = (const float*)d_in[7];
    const float* W3 = (const float*)d_in[8];  const float* b3 = (const float*)d_in[9];
    const float* U0 = (const float*)d_in[10]; const float* c0 = (const float*)d_in[11];
    const float* U1 = (const float*)d_in[12]; const float* c1 = (const float*)d_in[13];
    const float* U2 = (const float*)d_in[14]; const float* c2 = (const float*)d_in[15];
    const float* p0 = (const float*)d_in[16];
    const float* p1 = (const float*)d_in[17];
    const float* p2 = (const float*)d_in[18];
    float* out = (float*)d_out;

    char* w = (char*)d_ws;
    size_t off = 0;
    auto alloc = [&](size_t bytes) -> void* {
        void* p = w + off;
        off += (bytes + 255) / 256 * 256;
        return p;
    };
    // zero region: ecnt, ocur, focnt, fcur (contiguous -> ONE small fill)
    int*   ecnt = (int*)alloc((size_t)N0 * 4);
    int*   ocur = (int*)alloc((size_t)N0 * 4);
    int*   focnt = (int*)alloc((size_t)N0 * 4);
    int*   fcur  = (int*)alloc((size_t)N0 * 4);
    float* A1  = (float*)alloc((size_t)KP1 * KP1 * 4);
    float* A1T = (float*)alloc((size_t)KP1 * KP1 * 4);
    float* A2  = (float*)alloc((size_t)KP2 * KP2 * 4);
    float* A3  = (float*)alloc((size_t)KP3 * KP3 * 4);
    float* CG  = (float*)alloc((size_t)KP2 * KP3 * 4);
    unsigned short* Abf = (unsigned short*)alloc((size_t)2048 * 4096 * 2);
    unsigned short* Bbf = (unsigned short*)alloc((size_t)2048 * 4096 * 2);
    float* part = (float*)alloc((size_t)16 * N0 * HID * 4);   // 8.4 MB: covers S=16@KP1, S=32@KP2
    float* x0  = (float*)alloc((size_t)N0 * HID * 4);
    float* x1  = (float*)alloc((size_t)KP1 * HID * 4);
    float* x2  = (float*)alloc((size_t)KP2 * HID * 4);
    float* x3  = (float*)alloc((size_t)KP3 * HID * 4);
    float* xp  = (float*)alloc((size_t)KP1 * HID * 4);
    float* ua  = (float*)alloc((size_t)KP2 * HID * 4);
    float* ub  = (float*)alloc((size_t)KP1 * HID * 4);
    float* yb  = (float*)alloc((size_t)N0 * HID * 4);
    float* dv0 = (float*)alloc((size_t)N0 * 4);
    float* dv1 = (float*)alloc((size_t)KP1 * 4);
    float* dv2 = (float*)alloc((size_t)KP2 * 4);
    float* dv3 = (float*)alloc((size_t)KP3 * 4);
    int*   rkA = (int*)alloc((size_t)N0 * 4);
    int*   rkB = (int*)alloc((size_t)KP1 * 4);
    int*   rkC = (int*)alloc((size_t)KP2 * 4);
    int*   pm0 = (int*)alloc((size_t)KP1 * 4);
    int*   pm1 = (int*)alloc((size_t)KP2 * 4);
    int*   pm2 = (int*)alloc((size_t)KP3 * 4);
    int*   outoff  = (int*)alloc((size_t)N0 * 4);
    int*   foutoff = (int*)alloc((size_t)N0 * 4);
    int*   outlist  = (int*)alloc((size_t)NE * 4);
    int*   foutlist = (int*)alloc((size_t)NE * 4);
    (void)ws_size; (void)in_sizes; (void)n_in; (void)out_size;

    auto gcn_f = [&](const float* A, int n, const float* xin, int K, const float* W,
                     const float* bias, const float* dvv, int relu, float* outv, int S, int chunk,
                     const float* UP, const int* rkl, int kup) {
        k_xw2<32><<<(n + 7) / 8, 256, 0, stream>>>(xin, W, dvv, yb, n, K, UP, rkl, kup);
        dim3 g((n + 63) / 64, S);
        k_agg<float, 32><<<g, 256, 0, stream>>>(A, yb, part, n, n, chunk);
        k_aggfin<32><<<(n * 32 + 255) / 256, 256, 0, stream>>>(part, S, yb, dvv, bias, outv, n, relu);
    };
    auto pool = [&](const float* xin, const float* p, int n, int k, int* rkbuf, int* perm, float* xpo) {
        k_fill0_u32<<<16, 256, 0, stream>>>((unsigned*)rkbuf, (size_t)n);
        dim3 gr((n + 255) / 256, (n + RCH - 1) / RCH);
        k_rankscore<<<gr, 256, 0, stream>>>(xin, p, rkbuf, n);
        k_permpool2<<<(n + 255) / 256, 256, 0, stream>>>(xin, p, rkbuf, perm, xpo, n, k);
    };

    // degrees + out-CSR (dv0 fused into scan)
    k_fill0_u32<<<16, 256, 0, stream>>>((unsigned*)ecnt, (size_t)4 * N0);
    k_scatcnt<<<(NE + 255) / 256, 256, 0, stream>>>(ei, ecnt);
    k_scan1<<<1, 256, 0, stream>>>(ecnt, outoff, dv0);
    k_fillout<<<(NE + 255) / 256, 256, 0, stream>>>(ei, outoff, ocur, outlist);

    // ---- down path ----
    k_xw2sk<<<dim3(N0 / 8, 4), 256, 0, stream>>>(x, W0, part, N0, FIN, 384);
    k_xwred<<<(N0 * 32 + 255) / 256, 256, 0, stream>>>(part, 4, dv0, yb, N0);
    k_spagg<32, 0><<<N0, 256, 0, stream>>>(outoff, ecnt, outlist, yb, dv0, b0, x0);
    pool(x0, p0, N0, KP1, rkA, pm0, xp);

    // L0 augment+pool: row-centric sparse, LDS-accumulated
    k_fcount<<<(NE + 255) / 256, 256, 0, stream>>>(ei, rkA, focnt);
    k_scan1<<<1, 256, 0, stream>>>(focnt, foutoff, nullptr);
    k_ffill<<<(NE + 255) / 256, 256, 0, stream>>>(ei, rkA, foutoff, fcur, foutlist);
    k_spaug2<<<KP1, 256, 0, stream>>>(ecnt, outoff, outlist, focnt, foutoff, foutlist, pm0, A1, dv1);

    gcn_f(A1, KP1, xp, HID, W1, b1, dv1, 1, x1, 16, 128, nullptr, nullptr, 0);
    k_tr_f32<<<dim3(63, 63), 256, 0, stream>>>(A1, A1T, KP1);
    pool(x1, p1, KP1, KP2, rkB, pm1, xp);

    k_prepfb<<<dim3(1024, 2), 256, 0, stream>>>(A1, A1T, KP1, 2048, pm1, KP2, Abf, Bbf);
    k_fill0_u32<<<2048, 256, 0, stream>>>((unsigned*)A2, (size_t)KP2 * KP2);
    k_mfma_pool<<<dim3(8, 8, 4), 512, 0, stream>>>(Abf, Bbf, A2, 2048, KP2, 512);

    k_degf<<<KP2, 256, 0, stream>>>(A2, KP2, dv2);
    gcn_f(A2, KP2, xp, HID, W2, b2, dv2, 1, x2, 32, 32, nullptr, nullptr, 0);
    pool(x2, p2, KP2, KP3, rkC, pm2, xp);

    // L2 augment+pool: exact fp32, split-K (S=16); partials reuse Abf (idle here)
    {
        size_t tot = (size_t)KP2 * KP3;
        k_gcols<float><<<(int)((tot + 255) / 256), 256, 0, stream>>>(A2, pm2, CG, KP2, KP3);
        float* pbuf = (float*)Abf;
        k_gemm_pool_sk<<<dim3(8, 8, 16), 256, 0, stream>>>(A2, pm2, CG, pbuf, KP2, KP3, 64);
        k_gpfin<<<(KP3 * KP3 + 255) / 256, 256, 0, stream>>>(pbuf, 16, A3, KP3);
    }
    k_degf<<<KP3, 256, 0, stream>>>(A3, KP3, dv3);
    gcn_f(A3, KP3, xp, HID, W3, b3, dv3, 1, x3, 32, 16, nullptr, nullptr, 0);

    // ---- up path (unpool fused into xw2) ----
    gcn_f(A2, KP2, x2, HID, U0, c0, dv2, 1, ua, 32, 32, x3, rkC, KP3);
    gcn_f(A1, KP1, x1, HID, U1, c1, dv1, 1, ub, 16, 128, ua, rkB, KP2);

    // final layer: xw2 + CSR-gather aggregation with fused log-softmax epilogue
    k_xw2<16><<<(N0 + 15) / 16, 256, 0, stream>>>(x0, U2, dv0, yb, N0, HID, ub, rkA, KP1);
    k_spagg<16, 2><<<N0, 256, 0, stream>>>(outoff, ecnt, outlist, yb, dv0, c2, out);
}

// Round 22
// 372.301 us; speedup vs baseline: 1.0237x; 1.0237x over previous
//
#include <hip/hip_runtime.h>
#include <math.h>
#include <stddef.h>

#define N0   4096
#define NE   131072
#define FIN  1433
#define HID  32
#define NCLS 16
#define KP1  2000
#define KP2  1000
#define KP3  500
#define RCH  512

typedef __attribute__((ext_vector_type(8))) short bf16x8;
typedef __attribute__((ext_vector_type(4))) float f32x4;

// ---------------- basic utils ----------------

__global__ __launch_bounds__(256) void k_fill0_u32(unsigned* p, size_t n) {
    size_t i = (size_t)blockIdx.x * blockDim.x + threadIdx.x;
    size_t st = (size_t)gridDim.x * blockDim.x;
    for (; i < n; i += st) p[i] = 0u;
}

// count out-degrees only
__global__ __launch_bounds__(256) void k_scatcnt(const int* ei, int* ecnt) {
    int e = blockIdx.x * blockDim.x + threadIdx.x;
    if (e >= NE) return;
    int r = ei[e], c = ei[NE + e];
    if (r == c) return;
    atomicAdd(&ecnt[r], 1);
}

// exclusive prefix scan of one N0-length int array; optionally emits dv[i]=1/sqrt(d[i]+2)
__global__ __launch_bounds__(256) void k_scan1(const int* __restrict__ d, int* __restrict__ o,
                                               float* __restrict__ dv) {
    __shared__ int buf[N0];
    __shared__ int part[256];
    int tid = threadIdx.x;
    for (int t = tid; t < N0; t += 256) buf[t] = d[t];
    __syncthreads();
    int base = tid * (N0 / 256);
    int s = 0;
    #pragma unroll
    for (int j = 0; j < N0 / 256; j++) s += buf[base + j];
    part[tid] = s;
    __syncthreads();
    for (int offd = 1; offd < 256; offd <<= 1) {
        int v = (tid >= offd) ? part[tid - offd] : 0;
        __syncthreads();
        part[tid] += v;
        __syncthreads();
    }
    int run = (tid == 0) ? 0 : part[tid - 1];
    #pragma unroll
    for (int j = 0; j < N0 / 256; j++) {
        int tmp = buf[base + j];
        o[base + j] = run;
        run += tmp;
    }
    if (dv) {
        for (int t = tid; t < N0; t += 256)
            dv[t] = (float)(1.0 / sqrt((double)buf[t] + 2.0));
    }
}

// fill unfiltered out-CSR
__global__ __launch_bounds__(256) void k_fillout(const int* ei, const int* outoff, int* ocur, int* outlist) {
    int e = blockIdx.x * 256 + threadIdx.x;
    if (e >= NE) return;
    int u = ei[e], v = ei[NE + e];
    if (u == v) return;
    int s = atomicAdd(&ocur[u], 1);
    outlist[outoff[u] + s] = v;
}

// filtered counts: edges u->v with rk[v]<KP1
__global__ __launch_bounds__(256) void k_fcount(const int* ei, const int* rk, int* focnt) {
    int e = blockIdx.x * 256 + threadIdx.x;
    if (e >= NE) return;
    int u = ei[e], v = ei[NE + e];
    if (u == v) return;
    if (rk[v] < KP1) atomicAdd(&focnt[u], 1);
}

// fill filtered, rank-remapped out-lists
__global__ __launch_bounds__(256) void k_ffill(const int* ei, const int* rk, const int* foutoff,
                                               int* fcur, int* foutlist) {
    int e = blockIdx.x * 256 + threadIdx.x;
    if (e >= NE) return;
    int u = ei[e], v = ei[NE + e];
    if (u == v) return;
    int rv = rk[v];
    if (rv >= KP1) return;
    int s = atomicAdd(&fcur[u], 1);
    foutlist[foutoff[u] + s] = rv;
}

// row-centric sparse augment: A1[r1][:] = ((A0+I)^2)[perm[r1]][perm[:]], diag 0; dv1 fused.
__global__ __launch_bounds__(256) void k_spaug2(const int* __restrict__ ecnt, const int* __restrict__ outoff,
                                                const int* __restrict__ outlist,
                                                const int* __restrict__ focnt, const int* __restrict__ foutoff,
                                                const int* __restrict__ foutlist,
                                                const int* __restrict__ perm,
                                                float* __restrict__ A1, float* __restrict__ dv1) {
    __shared__ float rowacc[KP1];
    __shared__ float red[256];
    int r1 = blockIdx.x, tid = threadIdx.x;
    for (int j = tid; j < KP1; j += 256) rowacc[j] = 0.f;
    int pr1 = perm[r1];
    __syncthreads();
    int od = ecnt[pr1], ob = outoff[pr1];
    int g = tid >> 5, lane = tid & 31;
    for (int ki = g; ki < od; ki += 8) {
        int k = outlist[ob + ki];
        int fb = foutoff[k], fc = focnt[k];
        for (int j = lane; j < fc; j += 32) atomicAdd(&rowacc[foutlist[fb + j]], 1.f);
    }
    {
        int fb = foutoff[pr1], fc = focnt[pr1];
        for (int j = tid; j < fc; j += 256) atomicAdd(&rowacc[foutlist[fb + j]], 2.f);
    }
    __syncthreads();
    if (tid == 0) rowacc[r1] = 0.f;
    __syncthreads();
    float rs = 0.f;
    for (int j = tid * 4; j < KP1; j += 1024) {
        float4 v = *(const float4*)&rowacc[j];
        rs += v.x + v.y + v.z + v.w;
        *(float4*)&A1[(size_t)r1 * KP1 + j] = v;
    }
    red[tid] = rs; __syncthreads();
    for (int o = 128; o > 0; o >>= 1) {
        if (tid < o) red[tid] += red[tid + o];
        __syncthreads();
    }
    if (tid == 0) dv1[r1] = (float)(1.0 / sqrt((double)red[0] + 2.0));
}

// CSR-gather GCN aggregation over A0 with fused epilogue.
template <int NC, int MODE>
__global__ __launch_bounds__(256) void k_spagg(const int* __restrict__ outoff, const int* __restrict__ ecnt,
                                               const int* __restrict__ outlist,
                                               const float* __restrict__ y, const float* __restrict__ dvv,
                                               const float* __restrict__ bias, float* __restrict__ outp) {
    constexpr int G = 256 / NC;
    __shared__ float red[256];
    __shared__ float fin[NC];
    int i = blockIdx.x;
    int tid = threadIdx.x;
    int c = tid % NC, g = tid / NC;
    int od = ecnt[i], ob = outoff[i];
    float acc = 0.f;
    for (int j = g; j < od; j += G)
        acc += y[(size_t)outlist[ob + j] * NC + c];
    red[tid] = acc;
    __syncthreads();
    for (int o = G / 2; o > 0; o >>= 1) {
        if (g < o) red[tid] += red[tid + o * NC];
        __syncthreads();
    }
    if (tid < NC) {
        float di = dvv[i];
        float v = di * red[tid] + 2.f * di * y[(size_t)i * NC + tid] + bias[tid];
        if (MODE == 0) v = fmaxf(v, 0.f);
        fin[tid] = v;
    }
    __syncthreads();
    if (tid < NC) {
        if (MODE == 2) {
            float m = -1e30f;
            for (int cc = 0; cc < NC; cc++) m = fmaxf(m, fin[cc]);
            float se = 0.f;
            for (int cc = 0; cc < NC; cc++) se += expf(fin[cc] - m);
            outp[(size_t)i * NC + tid] = fin[tid] - m - logf(se);
        } else {
            outp[(size_t)i * NC + tid] = fin[tid];
        }
    }
}

// vectorized deg for f32 adjacency; entries are exact integers
__global__ __launch_bounds__(256) void k_degf(const float* A, int n, float* dv) {
    int i = blockIdx.x;
    const float* row = A + (size_t)i * n;
    float acc = 0.f;
    for (int j = threadIdx.x * 4; j < n; j += 256 * 4) {
        float4 w = *(const float4*)&row[j];
        acc += w.x + w.y + w.z + w.w;
    }
    __shared__ float red[256];
    red[threadIdx.x] = acc; __syncthreads();
    for (int off = 128; off > 0; off >>= 1) {
        if (threadIdx.x < off) red[threadIdx.x] += red[threadIdx.x + off];
        __syncthreads();
    }
    if (threadIdx.x == 0) dv[i] = (float)(1.0 / sqrt((double)red[0] + 2.0));
}

// tiled XW GEMM with fused dv scaling and optional fused unpool
template <int NC>
__global__ __launch_bounds__(256) void k_xw2(const float* __restrict__ X, const float* __restrict__ W,
                                             const float* __restrict__ dvv, float* __restrict__ YB,
                                             int M, int K,
                                             const float* __restrict__ UP, const int* __restrict__ rkl, int kup) {
    constexpr int BR = 256 / NC;
    constexpr int BK = 64;
    constexpr int XEL = BR * BK / 256;
    constexpr int WEL = BK * NC / 256;
    __shared__ float Xs[BR][BK + 4];
    __shared__ float Ws[BK][NC];
    int r0 = blockIdx.x * BR;
    int tid = threadIdx.x;
    int c = tid % NC, r = tid / NC;
    int xli = tid * XEL, xr = xli / BK, xc = xli % BK;
    int wli = tid * WEL, wk = wli / NC, wc = wli % NC;
    int grow = r0 + xr;
    int upr = -1;
    if (UP && grow < M) { int rr = rkl[grow]; if (rr < kup) upr = rr; }
    float acc = 0.f;

    for (int k0 = 0; k0 < K; k0 += BK) {
        __syncthreads();
        #pragma unroll
        for (int e = 0; e < XEL; e++) {
            int kk = k0 + xc + e;
            float v = (grow < M && kk < K) ? X[(size_t)grow * K + kk] : 0.f;
            if (upr >= 0 && kk < K) v += UP[(size_t)upr * K + kk];
            Xs[xr][xc + e] = v;
        }
        if (k0 + wk < K) {
            #pragma unroll
            for (int e = 0; e < WEL; e += 4)
                *(float4*)&Ws[wk][wc + e] = *(const float4*)&W[(size_t)(k0 + wk) * NC + wc + e];
        } else {
            #pragma unroll
            for (int e = 0; e < WEL; e++) Ws[wk][wc + e] = 0.f;
        }
        __syncthreads();
        #pragma unroll 8
        for (int k = 0; k < BK; k++) acc += Xs[r][k] * Ws[k][c];
    }
    int orow = r0 + r;
    if (orow < M) YB[(size_t)orow * NC + c] = dvv[orow] * acc;
}

// split-K variant for the large-K (FIN) layer
__global__ __launch_bounds__(256) void k_xw2sk(const float* __restrict__ X, const float* __restrict__ W,
                                               float* __restrict__ xwp, int M, int K, int chunk) {
    constexpr int NC = 32, BR = 8, BK = 64;
    __shared__ float Xs[BR][BK + 4];
    __shared__ float Ws[BK][NC];
    int r0 = blockIdx.x * BR;
    int s  = blockIdx.y;
    int kb = s * chunk, ke = min(kb + chunk, K);
    int tid = threadIdx.x;
    int c = tid % NC, r = tid / NC;
    int xli = tid * 2, xr = xli / BK, xc = xli % BK;
    int wli = tid * 8, wk = wli / NC, wc = wli % NC;
    int grow = r0 + xr;
    float acc = 0.f;

    for (int k0 = kb; k0 < ke; k0 += BK) {
        __syncthreads();
        #pragma unroll
        for (int e = 0; e < 2; e++) {
            int kk = k0 + xc + e;
            Xs[xr][xc + e] = (grow < M && kk < K) ? X[(size_t)grow * K + kk] : 0.f;
        }
        if (k0 + wk < K) {
            #pragma unroll
            for (int e = 0; e < 8; e += 4)
                *(float4*)&Ws[wk][wc + e] = *(const float4*)&W[(size_t)(k0 + wk) * NC + wc + e];
        } else {
            #pragma unroll
            for (int e = 0; e < 8; e++) Ws[wk][wc + e] = 0.f;
        }
        __syncthreads();
        #pragma unroll 8
        for (int k = 0; k < BK; k++) acc += Xs[r][k] * Ws[k][c];
    }
    int orow = r0 + r;
    if (orow < M) xwp[((size_t)s * M + orow) * NC + c] = acc;
}

// reduce split-K xw partials with dv scaling
__global__ __launch_bounds__(256) void k_xwred(const float* __restrict__ xwp, int S,
                                               const float* __restrict__ dvv, float* __restrict__ yb, int M) {
    int idx = blockIdx.x * 256 + threadIdx.x;
    if (idx >= M * 32) return;
    float s = 0.f;
    for (int t = 0; t < S; t++) s += xwp[(size_t)t * M * 32 + idx];
    yb[idx] = dvv[idx / 32] * s;
}

// ---------------- tiled split-K aggregation (dense f32 levels) ----------------

template <class T, int NC>
__global__ __launch_bounds__(256) void k_agg(const T* __restrict__ A, const float* __restrict__ y,
                                             float* __restrict__ part, int n, int M, int chunk) {
    constexpr int G   = 256 / NC;
    constexpr int RPT = 64 / G;
    __shared__ float At[64][72];
    __shared__ float ys[64][NC];
    int r0 = blockIdx.x * 64;
    int s  = blockIdx.y;
    int k_begin = s * chunk;
    int k_end   = min(k_begin + chunk, n);
    int tid = threadIdx.x;
    int c = tid % NC, g = tid / NC;
    int r = tid & 63, kq = tid >> 6;
    bool row_ok = (r0 + r) < M;
    float acc[RPT] = {};

    for (int k0 = k_begin; k0 < k_end; k0 += 64) {
        __syncthreads();
        #pragma unroll
        for (int q = 0; q < 4; q++) {
            int kl = kq * 16 + q * 4;
            float4 w = {0.f, 0.f, 0.f, 0.f};
            if (row_ok) w = *(const float4*)&A[(size_t)(r0 + r) * n + k0 + kl];
            At[kl + 0][r] = (k0 + kl + 0 < k_end) ? w.x : 0.f;
            At[kl + 1][r] = (k0 + kl + 1 < k_end) ? w.y : 0.f;
            At[kl + 2][r] = (k0 + kl + 2 < k_end) ? w.z : 0.f;
            At[kl + 3][r] = (k0 + kl + 3 < k_end) ? w.w : 0.f;
        }
        constexpr int NF4 = 64 * NC / 4;
        #pragma unroll
        for (int f = 0; f < NF4 / 256; f++) {
            int fi = tid + f * 256;
            int k = fi / (NC / 4), cb = fi % (NC / 4);
            float4 w = *(const float4*)&y[(size_t)(k0 + k) * NC + cb * 4];
            *(float4*)&ys[k][cb * 4] = w;
        }
        __syncthreads();
        for (int k = 0; k < 64; k++) {
            float yv = ys[k][c];
            #pragma unroll
            for (int i = 0; i < RPT; i += 4) {
                float4 a = *(const float4*)&At[k][g * RPT + i];
                acc[i + 0] += a.x * yv;
                acc[i + 1] += a.y * yv;
                acc[i + 2] += a.z * yv;
                acc[i + 3] += a.w * yv;
            }
        }
    }
    #pragma unroll
    for (int i = 0; i < RPT; i++) {
        int row = r0 + g * RPT + i;
        if (row < M) part[((size_t)s * M + row) * NC + c] = acc[i];
    }
}

template <int NC>
__global__ __launch_bounds__(256) void k_aggfin(const float* __restrict__ part, int S,
                                                const float* __restrict__ y, const float* __restrict__ dvv,
                                                const float* __restrict__ bias, float* __restrict__ out,
                                                int M, int relu) {
    int idx = blockIdx.x * blockDim.x + threadIdx.x;
    if (idx >= M * NC) return;
    int i = idx / NC, c = idx % NC;
    float sum = 0.f;
    for (int s = 0; s < S; s++) sum += part[(size_t)s * M * NC + idx];
    float di = dvv[i];
    float v = di * sum + 2.f * di * y[idx] + bias[c];
    if (relu) v = fmaxf(v, 0.f);
    out[idx] = v;
}

// ---------------- top-k pooling ----------------

__global__ __launch_bounds__(256) void k_rankscore(const float* __restrict__ x, const float* __restrict__ p,
                                                   int* __restrict__ rk, int n) {
    __shared__ float sj[RCH];
    float pv[HID];
    #pragma unroll
    for (int c = 0; c < HID; c++) pv[c] = p[c];
    float nrm = 0.f;
    #pragma unroll
    for (int c = 0; c < HID; c++) nrm += pv[c] * pv[c];
    nrm = sqrtf(nrm);
    int jb = blockIdx.y * RCH;
    int len = min(jb + RCH, n) - jb;
    for (int t = threadIdx.x; t < len; t += 256) {
        const float* xr = x + (size_t)(jb + t) * HID;
        float d = 0.f;
        #pragma unroll
        for (int c = 0; c < HID; c++) d += xr[c] * pv[c];
        sj[t] = tanhf(d / nrm);
    }
    __syncthreads();
    int i = blockIdx.x * 256 + threadIdx.x;
    if (i >= n) return;
    const float* xi = x + (size_t)i * HID;
    float di = 0.f;
    #pragma unroll
    for (int c = 0; c < HID; c++) di += xi[c] * pv[c];
    float si = tanhf(di / nrm);
    int r = 0;
    for (int j = 0; j < len; j += 4) {
        float4 v = *(const float4*)&sj[j];
        int jg = jb + j;
        r += (v.x > si) || (v.x == si && (jg + 0) < i);
        r += (v.y > si) || (v.y == si && (jg + 1) < i);
        r += (v.z > si) || (v.z == si && (jg + 2) < i);
        r += (v.w > si) || (v.w == si && (jg + 3) < i);
    }
    atomicAdd(&rk[i], r);
}

__global__ __launch_bounds__(256) void k_permpool2(const float* __restrict__ x, const float* __restrict__ p,
                                                   const int* __restrict__ rk, int* __restrict__ perm,
                                                   float* __restrict__ xp, int n, int k) {
    int i = blockIdx.x * 256 + threadIdx.x;
    if (i >= n) return;
    int r = rk[i];
    if (r >= k) return;
    perm[r] = i;
    float pv[HID];
    #pragma unroll
    for (int c = 0; c < HID; c++) pv[c] = p[c];
    float nrm = 0.f;
    #pragma unroll
    for (int c = 0; c < HID; c++) nrm += pv[c] * pv[c];
    nrm = sqrtf(nrm);
    const float* xi = x + (size_t)i * HID;
    float d = 0.f;
    #pragma unroll
    for (int c = 0; c < HID; c++) d += xi[c] * pv[c];
    float si = tanhf(d / nrm);
    const float4* xr = (const float4*)xi;
    float4* xpo = (float4*)(xp + (size_t)r * HID);
    #pragma unroll
    for (int c = 0; c < HID / 4; c++) {
        float4 v = xr[c];
        v.x *= si; v.y *= si; v.z *= si; v.w *= si;
        xpo[c] = v;
    }
}

// ---------------- fp32 augment+pool path (level 2; split-K, fused column gather) ----------------

__global__ __launch_bounds__(256) void k_gemm_pool_sk(const float* A, const int* perm,
                                                      float* part, int n, int kk, int chunk) {
    __shared__ float As[16][65];
    __shared__ float Bs[16][65];
    __shared__ int   pr[64];
    __shared__ int   pc[64];
    int r0 = blockIdx.y * 64, c0 = blockIdx.x * 64;
    int s  = blockIdx.z;
    int k_begin = s * chunk;
    int k_end   = min(k_begin + chunk, n);
    int tx = threadIdx.x % 16, ty = threadIdx.x / 16;

    for (int t = threadIdx.x; t < 64; t += 256) {
        int rg = r0 + t;
        pr[t] = (rg < kk) ? perm[rg] : -1;
        int cg = c0 + t;
        pc[t] = (cg < kk) ? perm[cg] : -1;
    }
    __syncthreads();

    float acc[4][4] = {};
    int cB = threadIdx.x % 64, kB = threadIdx.x / 64;

    for (int k0 = k_begin; k0 < k_end; k0 += 16) {
        for (int pass = 0; pass < 4; pass++) {
            int rr = ty + pass * 16;
            int kk_ = k0 + tx;
            int prow = pr[rr];
            float v = 0.f;
            if (prow >= 0 && kk_ < k_end) {
                v = A[(size_t)prow * n + kk_];
                if (prow == kk_) v += 1.f;
            }
            As[tx][rr] = v;
        }
        for (int pass = 0; pass < 4; pass++) {
            int k = kB + 4 * pass;
            int pcol = pc[cB];
            float v = 0.f;
            if (pcol >= 0 && (k0 + k) < k_end) {
                v = A[(size_t)(k0 + k) * n + pcol];
                if ((k0 + k) == pcol) v += 1.f;
            }
            Bs[k][cB] = v;
        }
        __syncthreads();
        for (int k = 0; k < 16; k++) {
            float a[4], b[4];
            #pragma unroll
            for (int i = 0; i < 4; i++) a[i] = As[k][ty * 4 + i];
            #pragma unroll
            for (int j = 0; j < 4; j++) b[j] = Bs[k][tx * 4 + j];
            #pragma unroll
            for (int i = 0; i < 4; i++)
                #pragma unroll
                for (int j = 0; j < 4; j++) acc[i][j] += a[i] * b[j];
        }
        __syncthreads();
    }
    for (int i = 0; i < 4; i++) {
        int rg = r0 + ty * 4 + i;
        if (rg >= kk) continue;
        for (int j = 0; j < 4; j++) {
            int cg = c0 + tx * 4 + j;
            if (cg >= kk) continue;
            part[((size_t)s * kk + rg) * kk + cg] = acc[i][j];
        }
    }
}

__global__ __launch_bounds__(256) void k_gpfin(const float* __restrict__ part, int S, float* __restrict__ Ap, int kk) {
    int idx = blockIdx.x * blockDim.x + threadIdx.x;
    if (idx >= kk * kk) return;
    int rg = idx / kk, cg = idx % kk;
    float sum = 0.f;
    for (int s = 0; s < S; s++) sum += part[(size_t)s * kk * kk + idx];
    Ap[idx] = (rg == cg) ? 0.f : sum;
}

// ---------------- MFMA augment+pool path (level 1) ----------------

__global__ __launch_bounds__(256) void k_tr_f32(const float* A, float* AT, int n) {
    __shared__ float t[32][33];
    int bx = blockIdx.x * 32, by = blockIdx.y * 32;
    int tx = threadIdx.x % 32, ty = threadIdx.x / 32;
    for (int p = 0; p < 4; p++) {
        int r = by + ty + p * 8, c = bx + tx;
        t[ty + p * 8][tx] = (r < n && c < n) ? A[(size_t)r * n + c] : 0.f;
    }
    __syncthreads();
    for (int p = 0; p < 4; p++) {
        int r = bx + ty + p * 8, c = by + tx;
        if (r < n && c < n) AT[(size_t)r * n + c] = t[tx][ty + p * 8];
    }
}

// f32 -> bf16 row-gather of (A+I) by perm, both panels in one dispatch
__global__ __launch_bounds__(256) void k_prepfb(const float* A, const float* AT,
                                                int n, int Kpad, const int* perm, int kk,
                                                unsigned short* dstA, unsigned short* dstB) {
    const float* src = blockIdx.y ? AT : A;
    unsigned short* dst = blockIdx.y ? dstB : dstA;
    int r = blockIdx.x;
    unsigned short* drow = dst + (size_t)r * Kpad;
    if (r >= kk) {
        for (int k = threadIdx.x; k < Kpad; k += 256) drow[k] = 0;
        return;
    }
    int pr = perm[r];
    const float* srow = src + (size_t)pr * n;
    for (int k = threadIdx.x; k < Kpad; k += 256) {
        float v = (k < n) ? srow[k] : 0.f;
        if (k == pr) v += 1.f;
        drow[k] = (unsigned short)(__float_as_uint(v) >> 16);
    }
}

// 8-wave 128x128 tile split-K MFMA; exact-integer fp32 atomicAdd; diag skipped (pre-zeroed dst)
__global__ __launch_bounds__(512) void k_mfma_pool(const unsigned short* Abf, const unsigned short* Bbf,
                                                   float* Ap, int Kpad, int kk, int chunk) {
    __shared__ short As[128 * 64];
    __shared__ short Bs[128 * 64];
    int r0 = blockIdx.y * 128, c0 = blockIdx.x * 128;
    int z0 = blockIdx.z * chunk;
    int tid = threadIdx.x;
    int l = tid & 63, w = tid >> 6;
    int wm = w >> 2, wn = w & 3;
    f32x4 acc[4][2] = {};

    for (int k0 = z0; k0 < z0 + chunk; k0 += 64) {
        __syncthreads();
        #pragma unroll
        for (int p = 0; p < 2; p++) {
            int row = p * 64 + (tid >> 3);
            int ch  = tid & 7;
            int byte = row * 128 + ((ch * 16) ^ ((row & 7) << 4));
            bf16x8 va = *(const bf16x8*)&Abf[(size_t)(r0 + row) * Kpad + k0 + ch * 8];
            *(bf16x8*)((char*)As + byte) = va;
            bf16x8 vb = *(const bf16x8*)&Bbf[(size_t)(c0 + row) * Kpad + k0 + ch * 8];
            *(bf16x8*)((char*)Bs + byte) = vb;
        }
        __syncthreads();
        #pragma unroll
        for (int h = 0; h < 2; h++) {
            bf16x8 af[4], bfr[2];
            #pragma unroll
            for (int i = 0; i < 4; i++) {
                int row = wm * 64 + i * 16 + (l & 15);
                int byte = row * 128 + ((h * 64 + (l >> 4) * 16) ^ ((row & 7) << 4));
                af[i] = *(const bf16x8*)((const char*)As + byte);
            }
            #pragma unroll
            for (int j = 0; j < 2; j++) {
                int row = wn * 32 + j * 16 + (l & 15);
                int byte = row * 128 + ((h * 64 + (l >> 4) * 16) ^ ((row & 7) << 4));
                bfr[j] = *(const bf16x8*)((const char*)Bs + byte);
            }
            #pragma unroll
            for (int i = 0; i < 4; i++)
                #pragma unroll
                for (int j = 0; j < 2; j++)
                    acc[i][j] = __builtin_amdgcn_mfma_f32_16x16x32_bf16(af[i], bfr[j], acc[i][j], 0, 0, 0);
        }
    }
    #pragma unroll
    for (int i = 0; i < 4; i++) {
        #pragma unroll
        for (int j = 0; j < 2; j++) {
            int cg = c0 + wn * 32 + j * 16 + (l & 15);
            if (cg < kk) {
                #pragma unroll
                for (int q = 0; q < 4; q++) {
                    int rg = r0 + wm * 64 + i * 16 + (l >> 4) * 4 + q;
                    if (rg < kk && rg != cg) atomicAdd(&Ap[(size_t)rg * kk + cg], acc[i][j][q]);
                }
            }
        }
    }
}

// ---------------- host ----------------

extern "C" void kernel_launch(void* const* d_in, const int* in_sizes, int n_in,
                              void* d_out, int out_size, void* d_ws, size_t ws_size,
                              hipStream_t stream) {
    const float* x  = (const float*)d_in[0];
    const int*   ei = (const int*)d_in[1];
    const float* W0 = (const float*)d_in[2];  const float* b0 = (const float*)d_in[3];
    const float* W1 = (const float*)d_in[4];  const float* b1 = (const float*)d_in[5];
    const float* W2 = (const float*)d_in[6];  const float* b2 = (const float*)d_in[7];
    const float* W3 = (const float*)d_in[8];  const float* b3 = (const float*)d_in[9];
    const float* U0 = (const float*)d_in[10]; const float* c0 = (const float*)d_in[11];
    const float* U1 = (const float*)d_in[12]; const float* c1 = (const float*)d_in[13];
    const float* U2 = (const float*)d_in[14]; const float* c2 = (const float*)d_in[15];
    const float* p0 = (const float*)d_in[16];
    const float* p1 = (const float*)d_in[17];
    const float* p2 = (const float*)d_in[18];
    float* out = (float*)d_out;

    char* w = (char*)d_ws;
    size_t off = 0;
    auto alloc = [&](size_t bytes) -> void* {
        void* p = w + off;
        off += (bytes + 255) / 256 * 256;
        return p;
    };
    // contiguous zero region: ecnt, ocur, focnt, fcur, rkA, rkB, rkC -> ONE fill
    int*   ecnt = (int*)alloc((size_t)N0 * 4);
    int*   ocur = (int*)alloc((size_t)N0 * 4);
    int*   focnt = (int*)alloc((size_t)N0 * 4);
    int*   fcur  = (int*)alloc((size_t)N0 * 4);
    int*   rkA = (int*)alloc((size_t)N0 * 4);
    int*   rkB = (int*)alloc((size_t)KP1 * 4);
    int*   rkC = (int*)alloc((size_t)KP2 * 4);
    size_t zero_end = off;
    float* A1  = (float*)alloc((size_t)KP1 * KP1 * 4);
    float* A1T = (float*)alloc((size_t)KP1 * KP1 * 4);
    float* A2  = (float*)alloc((size_t)KP2 * KP2 * 4);
    float* A3  = (float*)alloc((size_t)KP3 * KP3 * 4);
    unsigned short* Abf = (unsigned short*)alloc((size_t)2048 * 4096 * 2);
    unsigned short* Bbf = (unsigned short*)alloc((size_t)2048 * 4096 * 2);
    float* part = (float*)alloc((size_t)16 * N0 * HID * 4);
    float* x0  = (float*)alloc((size_t)N0 * HID * 4);
    float* x1  = (float*)alloc((size_t)KP1 * HID * 4);
    float* x2  = (float*)alloc((size_t)KP2 * HID * 4);
    float* x3  = (float*)alloc((size_t)KP3 * HID * 4);
    float* xp  = (float*)alloc((size_t)KP1 * HID * 4);
    float* ua  = (float*)alloc((size_t)KP2 * HID * 4);
    float* ub  = (float*)alloc((size_t)KP1 * HID * 4);
    float* yb  = (float*)alloc((size_t)N0 * HID * 4);
    float* dv0 = (float*)alloc((size_t)N0 * 4);
    float* dv1 = (float*)alloc((size_t)KP1 * 4);
    float* dv2 = (float*)alloc((size_t)KP2 * 4);
    float* dv3 = (float*)alloc((size_t)KP3 * 4);
    int*   pm0 = (int*)alloc((size_t)KP1 * 4);
    int*   pm1 = (int*)alloc((size_t)KP2 * 4);
    int*   pm2 = (int*)alloc((size_t)KP3 * 4);
    int*   outoff  = (int*)alloc((size_t)N0 * 4);
    int*   foutoff = (int*)alloc((size_t)N0 * 4);
    int*   outlist  = (int*)alloc((size_t)NE * 4);
    int*   foutlist = (int*)alloc((size_t)NE * 4);
    (void)ws_size; (void)in_sizes; (void)n_in; (void)out_size;

    auto gcn_f = [&](const float* A, int n, const float* xin, int K, const float* W,
                     const float* bias, const float* dvv, int relu, float* outv, int S, int chunk,
                     const float* UP, const int* rkl, int kup) {
        k_xw2<32><<<(n + 7) / 8, 256, 0, stream>>>(xin, W, dvv, yb, n, K, UP, rkl, kup);
        dim3 g((n + 63) / 64, S);
        k_agg<float, 32><<<g, 256, 0, stream>>>(A, yb, part, n, n, chunk);
        k_aggfin<32><<<(n * 32 + 255) / 256, 256, 0, stream>>>(part, S, yb, dvv, bias, outv, n, relu);
    };
    auto pool = [&](const float* xin, const float* p, int n, int k, int* rkbuf, int* perm, float* xpo) {
        dim3 gr((n + 255) / 256, (n + RCH - 1) / RCH);
        k_rankscore<<<gr, 256, 0, stream>>>(xin, p, rkbuf, n);
        k_permpool2<<<(n + 255) / 256, 256, 0, stream>>>(xin, p, rkbuf, perm, xpo, n, k);
    };

    // one fill covers all zero-init buffers (rk buffers written once per call via int atomics)
    k_fill0_u32<<<32, 256, 0, stream>>>((unsigned*)ecnt, zero_end / 4);
    k_scatcnt<<<(NE + 255) / 256, 256, 0, stream>>>(ei, ecnt);
    k_scan1<<<1, 256, 0, stream>>>(ecnt, outoff, dv0);
    k_fillout<<<(NE + 255) / 256, 256, 0, stream>>>(ei, outoff, ocur, outlist);

    // ---- down path ----
    k_xw2sk<<<dim3(N0 / 8, 4), 256, 0, stream>>>(x, W0, part, N0, FIN, 384);
    k_xwred<<<(N0 * 32 + 255) / 256, 256, 0, stream>>>(part, 4, dv0, yb, N0);
    k_spagg<32, 0><<<N0, 256, 0, stream>>>(outoff, ecnt, outlist, yb, dv0, b0, x0);
    pool(x0, p0, N0, KP1, rkA, pm0, xp);

    // L0 augment+pool: row-centric sparse, LDS-accumulated
    k_fcount<<<(NE + 255) / 256, 256, 0, stream>>>(ei, rkA, focnt);
    k_scan1<<<1, 256, 0, stream>>>(focnt, foutoff, nullptr);
    k_ffill<<<(NE + 255) / 256, 256, 0, stream>>>(ei, rkA, foutoff, fcur, foutlist);
    k_spaug2<<<KP1, 256, 0, stream>>>(ecnt, outoff, outlist, focnt, foutoff, foutlist, pm0, A1, dv1);

    gcn_f(A1, KP1, xp, HID, W1, b1, dv1, 1, x1, 16, 128, nullptr, nullptr, 0);
    k_tr_f32<<<dim3(63, 63), 256, 0, stream>>>(A1, A1T, KP1);
    pool(x1, p1, KP1, KP2, rkB, pm1, xp);

    k_prepfb<<<dim3(1024, 2), 256, 0, stream>>>(A1, A1T, KP1, 2048, pm1, KP2, Abf, Bbf);
    k_fill0_u32<<<2048, 256, 0, stream>>>((unsigned*)A2, (size_t)KP2 * KP2);
    k_mfma_pool<<<dim3(8, 8, 4), 512, 0, stream>>>(Abf, Bbf, A2, 2048, KP2, 512);

    k_degf<<<KP2, 256, 0, stream>>>(A2, KP2, dv2);
    gcn_f(A2, KP2, xp, HID, W2, b2, dv2, 1, x2, 32, 32, nullptr, nullptr, 0);
    pool(x2, p2, KP2, KP3, rkC, pm2, xp);

    // L2 augment+pool: exact fp32, split-K (S=16), fused column gather; partials reuse Abf
    {
        float* pbuf = (float*)Abf;
        k_gemm_pool_sk<<<dim3(8, 8, 16), 256, 0, stream>>>(A2, pm2, pbuf, KP2, KP3, 64);
        k_gpfin<<<(KP3 * KP3 + 255) / 256, 256, 0, stream>>>(pbuf, 16, A3, KP3);
    }
    k_degf<<<KP3, 256, 0, stream>>>(A3, KP3, dv3);
    gcn_f(A3, KP3, xp, HID, W3, b3, dv3, 1, x3, 32, 16, nullptr, nullptr, 0);

    // ---- up path (unpool fused into xw2) ----
    gcn_f(A2, KP2, x2, HID, U0, c0, dv2, 1, ua, 32, 32, x3, rkC, KP3);
    gcn_f(A1, KP1, x1, HID, U1, c1, dv1, 1, ub, 16, 128, ua, rkB, KP2);

    // final layer: xw2 + CSR-gather aggregation with fused log-softmax epilogue
    k_xw2<16><<<(N0 + 15) / 16, 256, 0, stream>>>(x0, U2, dv0, yb, N0, HID, ub, rkA, KP1);
    k_spagg<16, 2><<<N0, 256, 0, stream>>>(outoff, ecnt, outlist, yb, dv0, c2, out);
}